// Round 3
// baseline (80.190 us; speedup 1.0000x reference)
//
#include <hip/hip_runtime.h>

// Per-pixel Gaussian RBF voting, separable form:
//   field[c,x,y] = sum_n (exp(-dx^2 k)*v[c,n]) * exp(-dy^2 k)
// Floor: 2 FMA/pixel/center = 5.37e8 FLOP -> ~3.4 us on fp32 VALU (no fp32 MFMA).

constexpr int N = 128;
constexpr int W = 1024;
constexpr int L = 1024;
constexpr float SIGMA = 32.0f;

constexpr int TX = 8;        // x rows per block (exp overhead = 2/TX = 25% of FMA cyc)
constexpr int THREADS = 256;
constexpr int TY = THREADS;  // one y per thread -> 512 blocks = 2 blocks/CU = 2 waves/SIMD

__global__ __launch_bounds__(THREADS)
void rbf_field_kernel(const float* __restrict__ v,   // [2][N]
                      const int*   __restrict__ xc,  // [N]
                      const int*   __restrict__ yc,  // [N]
                      float*       __restrict__ out) // [2][W][L]
{
    // sB[n][j]: j in [0,16): c = j>>3, i = j&7 -> exp(-dx^2 k) * v[c][n]
    __shared__ __align__(16) float sB[N][2 * TX];
    __shared__ float sYc[N];

    const int tid = threadIdx.x;
    const int x0 = blockIdx.x * TX;
    const int y  = blockIdx.y * TY + tid;

    constexpr float kInv = 1.0f / (2.0f * SIGMA * SIGMA);

    if (tid < N) sYc[tid] = (float)yc[tid];

    // Fill sB: 2048 entries, 8 per thread, consecutive -> coalesced
    #pragma unroll
    for (int k = 0; k < (N * 2 * TX) / THREADS; ++k) {
        int idx = tid + k * THREADS;
        int n = idx >> 4;
        int j = idx & 15;
        int c = j >> 3;
        int i = j & 7;
        float dx = (float)(x0 + i - xc[n]);
        sB[n][j] = __expf(-dx * dx * kInv) * v[c * N + n];
    }
    __syncthreads();

    float acc[TX][2];
    #pragma unroll
    for (int i = 0; i < TX; ++i) {
        acc[i][0] = 0.0f;
        acc[i][1] = 0.0f;
    }

    const float yf = (float)y;

    #pragma unroll 4
    for (int n = 0; n < N; ++n) {
        float dy = yf - sYc[n];
        float wy = __expf(-dy * dy * kInv);

        // 16 contiguous LDS floats, wave-uniform address -> broadcast ds_read_b128
        #pragma unroll
        for (int i = 0; i < TX; ++i) {
            acc[i][0] += sB[n][i]      * wy;  // channel 0
            acc[i][1] += sB[n][TX + i] * wy;  // channel 1
        }
    }

    // Store: out[c][x][y]; across lanes y is consecutive -> fully coalesced dwords
    #pragma unroll
    for (int c = 0; c < 2; ++c) {
        #pragma unroll
        for (int i = 0; i < TX; ++i) {
            out[(size_t)c * W * L + (size_t)(x0 + i) * L + y] = acc[i][c];
        }
    }
}

extern "C" void kernel_launch(void* const* d_in, const int* in_sizes, int n_in,
                              void* d_out, int out_size, void* d_ws, size_t ws_size,
                              hipStream_t stream) {
    const float* v  = (const float*)d_in[0];  // init_vectors [2][128] fp32
    const int*   xc = (const int*)d_in[1];    // x_coord [128] int32
    const int*   yc = (const int*)d_in[2];    // y_coord [128] int32
    float* out = (float*)d_out;               // [1][2][1024][1024] fp32

    dim3 grid(W / TX, L / TY);   // (128, 4) = 512 blocks -> 2 blocks/CU
    rbf_field_kernel<<<grid, THREADS, 0, stream>>>(v, xc, yc, out);
}